// Round 1
// baseline (14043.016 us; speedup 1.0000x reference)
//
#include <hip/hip_runtime.h>
#include <cmath>

#define NSN 50000
#define NTN 50000
#define EE  500000

// ---------------------------------------------------------------- transpose
// dst[K][N] = src[N][K], batched via blockIdx.z. block (32,8)
__global__ void transpose_k(const float* __restrict__ src, float* __restrict__ dst,
                            int N, int K) {
  __shared__ float tl[32][33];
  const float* s = src + (size_t)blockIdx.z * N * K;
  float* d = dst + (size_t)blockIdx.z * N * K;
  int x = blockIdx.x * 32 + threadIdx.x;
  int y0 = blockIdx.y * 32;
  for (int i = threadIdx.y; i < 32; i += 8) {
    int y = y0 + i;
    if (y < N && x < K) tl[i][threadIdx.x] = s[(size_t)y * K + x];
  }
  __syncthreads();
  int x2 = y0 + threadIdx.x;      // N dim of output
  int yb = blockIdx.x * 32;       // K dim of output
  for (int i = threadIdx.y; i < 32; i += 8) {
    int y = yb + i;
    if (y < K && x2 < N) d[(size_t)y * N + x2] = tl[threadIdx.x][i];
  }
}

// ------------------------------------------------- combined wr (+transpose)
// z = l*2+d ; d=0: rel 0+3 (dst=source), d=1: rel 1+2 (dst=target)
__global__ void combine_wr_k(const float* __restrict__ wr, const float* __restrict__ bl,
                             float* __restrict__ wrcT, float* __restrict__ blc) {
  int z = blockIdx.y;
  int l = z >> 1, dd = z & 1;
  int r1 = dd ? 1 : 0, r2 = dd ? 2 : 3;
  int idx = blockIdx.x * 256 + threadIdx.x;
  if (idx < 16384) {
    int k = idx >> 7, n = idx & 127;
    float v = wr[((size_t)(l * 4 + r1) * 128 + n) * 128 + k] +
              wr[((size_t)(l * 4 + r2) * 128 + n) * 128 + k];
    wrcT[(size_t)z * 16384 + idx] = v;
    if (idx < 128) blc[z * 128 + idx] = bl[(l * 4 + r1) * 128 + idx] + bl[(l * 4 + r2) * 128 + idx];
  }
}

// ------------------------------------------------------------------- counts
__global__ void count_k(const int* __restrict__ col, int* __restrict__ cnt, int E) {
  int i = blockIdx.x * 256 + threadIdx.x;
  if (i < E) atomicAdd(&cnt[col[i]], 1);
}
__global__ void rcnt_k(const int* __restrict__ cnt, float* __restrict__ rc, int n) {
  int i = blockIdx.x * 256 + threadIdx.x;
  if (i < n) rc[i] = 1.f / (float)max(cnt[i], 1);
}

// ------------------------------------------------------------------ scatter
__global__ void scatter_k(const float* __restrict__ src, const int* __restrict__ ei,
                          float* __restrict__ sum, int E) {
  int idx = blockIdx.x * 256 + threadIdx.x;
  int e = idx >> 5;
  if (e >= E) return;
  int c = (idx & 31) << 2;
  int r = ei[e], cl = ei[E + e];
  float4 v = *reinterpret_cast<const float4*>(src + (size_t)r * 128 + c);
  float* d = sum + (size_t)cl * 128 + c;
  atomicAdd(d + 0, v.x); atomicAdd(d + 1, v.y);
  atomicAdd(d + 2, v.z); atomicAdd(d + 3, v.w);
}

// --------------------------------------------------------------------- GEMM
// C[M x 128] = op( (A .* rs[row]) @ WT )   WT is K x 128 (pre-transposed)
// MODE 0: C = acc + bias            MODE 1: C += acc
// MODE 2: C = relu(0.5*(C+acc)+res) MODE 3: C = relu(acc + bias)
template <int MODE>
__global__ __launch_bounds__(256) void gemm_k(
    const float* __restrict__ A, const float* __restrict__ rs,
    const float* __restrict__ WT, const float* __restrict__ bias,
    float* __restrict__ C, const float* __restrict__ res, int M, int K) {
  __shared__ float As[32][132];
  __shared__ float Ws[32][132];
  int m0 = blockIdx.x * 128;
  int t = threadIdx.x;
  int tx = t & 15, ty = t >> 4;   // cols tx*8.. , rows ty*8..
  float acc[8][8] = {};
  for (int kb = 0; kb < K; kb += 32) {
    {
      int k = t & 31, mr = t >> 5;
      int gk = kb + k;
      #pragma unroll
      for (int m = mr; m < 128; m += 8) {
        int gm = m0 + m;
        float v = 0.f;
        if (gm < M && gk < K) {
          v = A[(size_t)gm * K + gk];
          if (rs) v *= rs[gm];
        }
        As[k][m] = v;
      }
    }
    {
      int n = t & 127, kk = t >> 7;
      #pragma unroll
      for (int k2 = kk; k2 < 32; k2 += 2) {
        int gk = kb + k2;
        Ws[k2][n] = (gk < K) ? WT[(size_t)gk * 128 + n] : 0.f;
      }
    }
    __syncthreads();
    #pragma unroll
    for (int k = 0; k < 32; ++k) {
      float a[8], b[8];
      *(float4*)&a[0] = *(const float4*)&As[k][ty * 8];
      *(float4*)&a[4] = *(const float4*)&As[k][ty * 8 + 4];
      *(float4*)&b[0] = *(const float4*)&Ws[k][tx * 8];
      *(float4*)&b[4] = *(const float4*)&Ws[k][tx * 8 + 4];
      #pragma unroll
      for (int i = 0; i < 8; ++i)
        #pragma unroll
        for (int j = 0; j < 8; ++j) acc[i][j] = fmaf(a[i], b[j], acc[i][j]);
    }
    __syncthreads();
  }
  #pragma unroll
  for (int i = 0; i < 8; ++i) {
    int gm = m0 + ty * 8 + i;
    if (gm >= M) continue;
    float* cp = C + (size_t)gm * 128 + tx * 8;
    const float* rp = res ? res + (size_t)gm * 128 + tx * 8 : nullptr;
    float o[8];
    #pragma unroll
    for (int j = 0; j < 8; ++j) {
      float v = acc[i][j];
      if (MODE == 0 || MODE == 3) { if (bias) v += bias[tx * 8 + j]; }
      if (MODE == 1 || MODE == 2) v += cp[j];
      if (MODE == 2) v = 0.5f * v + (rp ? rp[j] : 0.f);
      if (MODE == 2 || MODE == 3) v = fmaxf(v, 0.f);
      o[j] = v;
    }
    *(float4*)cp = make_float4(o[0], o[1], o[2], o[3]);
    *(float4*)(cp + 4) = make_float4(o[4], o[5], o[6], o[7]);
  }
}

// ---------------------------------------------------------------- edge head
// fully fused: gather -> gate MLP -> sigmoid combine -> 3-layer MLP -> out
__global__ __launch_bounds__(256) void edge_head_k(
    const float* __restrict__ hs, const float* __restrict__ ht,
    const int* __restrict__ ei, const float* __restrict__ ea,
    const float* __restrict__ gw1T, const float* __restrict__ gb1,
    const float* __restrict__ gw2, const float* __restrict__ gb2,
    const float* __restrict__ mw1T, const float* __restrict__ mb1,
    const float* __restrict__ mw2T, const float* __restrict__ mb2,
    const float* __restrict__ mw3, const float* __restrict__ mb3,
    float* __restrict__ out, int Etot) {
  __shared__ float catT[256][36];   // [k][e]  k<256 : cat, later k<160 : feat
  __shared__ float h1T[128][36];    // [j][e]  (XOR-swizzled on e)
  __shared__ float h2T[64][36];
  __shared__ float gbuf[32];
  __shared__ int eidx[64];
  int t = threadIdx.x;
  int e0 = blockIdx.x * 32;
  if (t < 32) eidx[t] = ei[e0 + t];
  else if (t < 64) eidx[t] = ei[Etot + e0 + (t - 32)];
  __syncthreads();
  // P0: stage cat = [src_h | tgt_h]
  for (int i = t; i < 32 * 128; i += 256) {
    int e = i >> 7, c = i & 127;
    catT[c][e] = hs[(size_t)eidx[e] * 128 + c];
    catT[128 + c][e] = ht[(size_t)eidx[32 + e] * 128 + c];
  }
  __syncthreads();
  int tx = t & 15, ty = t >> 4;   // j = tx*8.., e = ty*2..
  // P1: gate hidden (K=256)
  {
    float acc0[8] = {}, acc1[8] = {};
    #pragma unroll 2
    for (int k = 0; k < 256; ++k) {
      float2 a = *(const float2*)&catT[k][ty * 2];
      float4 w0 = __ldg((const float4*)(gw1T + (size_t)k * 128 + tx * 8));
      float4 w1 = __ldg((const float4*)(gw1T + (size_t)k * 128 + tx * 8 + 4));
      float wv[8] = {w0.x, w0.y, w0.z, w0.w, w1.x, w1.y, w1.z, w1.w};
      #pragma unroll
      for (int j = 0; j < 8; ++j) {
        acc0[j] = fmaf(a.x, wv[j], acc0[j]);
        acc1[j] = fmaf(a.y, wv[j], acc1[j]);
      }
    }
    int cx = 4 * (tx & 7);
    #pragma unroll
    for (int j = 0; j < 8; ++j) {
      float b = gb1[tx * 8 + j];
      h1T[tx * 8 + j][(ty * 2) ^ cx] = fmaxf(acc0[j] + b, 0.f);
      h1T[tx * 8 + j][(ty * 2 + 1) ^ cx] = fmaxf(acc1[j] + b, 0.f);
    }
  }
  __syncthreads();
  // P2: gate scalar
  {
    int e = t >> 3, jl = t & 7;
    float s = 0.f;
    for (int j = jl; j < 128; j += 8) s += gw2[j] * h1T[j][e ^ (4 * ((j >> 3) & 7))];
    s += __shfl_xor(s, 1, 64); s += __shfl_xor(s, 2, 64); s += __shfl_xor(s, 4, 64);
    if (jl == 0) gbuf[e] = 1.f / (1.f + expf(-(s + gb2[0])));
  }
  __syncthreads();
  // P3: combined -> catT[0..127], edge_attr -> catT[128..159]
  for (int i = t; i < 32 * 128; i += 256) {
    int e = i >> 7, c = i & 127;
    float g = gbuf[e];
    catT[c][e] = catT[c][e] * g + catT[128 + c][e] * (1.f - g);
  }
  __syncthreads();
  for (int i = t; i < 32 * 32; i += 256) {
    int e = i >> 5, c = i & 31;
    catT[128 + c][e] = ea[(size_t)(e0 + e) * 32 + c];
  }
  __syncthreads();
  // P4: mlp layer1 (K=160) -> h1T
  {
    float acc0[8] = {}, acc1[8] = {};
    #pragma unroll 2
    for (int k = 0; k < 160; ++k) {
      float2 a = *(const float2*)&catT[k][ty * 2];
      float4 w0 = __ldg((const float4*)(mw1T + (size_t)k * 128 + tx * 8));
      float4 w1 = __ldg((const float4*)(mw1T + (size_t)k * 128 + tx * 8 + 4));
      float wv[8] = {w0.x, w0.y, w0.z, w0.w, w1.x, w1.y, w1.z, w1.w};
      #pragma unroll
      for (int j = 0; j < 8; ++j) {
        acc0[j] = fmaf(a.x, wv[j], acc0[j]);
        acc1[j] = fmaf(a.y, wv[j], acc1[j]);
      }
    }
    int cx = 4 * (tx & 7);
    #pragma unroll
    for (int j = 0; j < 8; ++j) {
      float b = mb1[tx * 8 + j];
      h1T[tx * 8 + j][(ty * 2) ^ cx] = fmaxf(acc0[j] + b, 0.f);
      h1T[tx * 8 + j][(ty * 2 + 1) ^ cx] = fmaxf(acc1[j] + b, 0.f);
    }
  }
  __syncthreads();
  // P5: mlp layer2 (K=128, N=64) -> h2T
  {
    int tx2 = t & 7, ty2 = t >> 3;   // j = tx2*8.., e = ty2
    float acc[8] = {};
    #pragma unroll 2
    for (int k = 0; k < 128; ++k) {
      float a = h1T[k][ty2 ^ (4 * ((k >> 3) & 7))];
      float4 w0 = __ldg((const float4*)(mw2T + (size_t)k * 64 + tx2 * 8));
      float4 w1 = __ldg((const float4*)(mw2T + (size_t)k * 64 + tx2 * 8 + 4));
      float wv[8] = {w0.x, w0.y, w0.z, w0.w, w1.x, w1.y, w1.z, w1.w};
      #pragma unroll
      for (int j = 0; j < 8; ++j) acc[j] = fmaf(a, wv[j], acc[j]);
    }
    int cx = 4 * (tx2 & 7);
    #pragma unroll
    for (int j = 0; j < 8; ++j)
      h2T[tx2 * 8 + j][ty2 ^ cx] = fmaxf(acc[j] + mb2[tx2 * 8 + j], 0.f);
  }
  __syncthreads();
  // P6: output (K=64, N=2)
  if (t < 64) {
    int e = t & 31, o = t >> 5;
    float s = mb3[o];
    for (int k = 0; k < 64; ++k) s += h2T[k][e ^ (4 * ((k >> 3) & 7))] * mw3[o * 64 + k];
    out[(size_t)(e0 + e) * 2 + o] = s;
  }
}

// ------------------------------------------------------------------- launch
extern "C" void kernel_launch(void* const* d_in, const int* in_sizes, int n_in,
                              void* d_out, int out_size, void* d_ws, size_t ws_size,
                              hipStream_t stream) {
  const float* x_source = (const float*)d_in[0];
  const float* x_target = (const float*)d_in[1];
  const float* edge_attr = (const float*)d_in[2];
  const float* enc_s_w1 = (const float*)d_in[3];
  const float* enc_s_b1 = (const float*)d_in[4];
  const float* enc_s_w2 = (const float*)d_in[5];
  const float* enc_s_b2 = (const float*)d_in[6];
  const float* enc_t_w1 = (const float*)d_in[7];
  const float* enc_t_b1 = (const float*)d_in[8];
  const float* enc_t_w2 = (const float*)d_in[9];
  const float* enc_t_b2 = (const float*)d_in[10];
  const float* conv_wl = (const float*)d_in[11];
  const float* conv_bl = (const float*)d_in[12];
  const float* conv_wr = (const float*)d_in[13];
  const float* gate_w1 = (const float*)d_in[14];
  const float* gate_b1 = (const float*)d_in[15];
  const float* gate_w2 = (const float*)d_in[16];
  const float* gate_b2 = (const float*)d_in[17];
  const float* mlp_w1 = (const float*)d_in[18];
  const float* mlp_b1 = (const float*)d_in[19];
  const float* mlp_w2 = (const float*)d_in[20];
  const float* mlp_b2 = (const float*)d_in[21];
  const float* mlp_w3 = (const float*)d_in[22];
  const float* mlp_b3 = (const float*)d_in[23];
  const int* ei_ss = (const int*)d_in[24];
  const int* ei_tt = (const int*)d_in[25];
  const int* ei_st = (const int*)d_in[26];
  const int* ei_ts = (const int*)d_in[27];
  float* out = (float*)d_out;

  float* w = (float*)d_ws;
  size_t off = 0;
  auto alloc = [&](size_t n) { float* p = w + off; off += n; return p; };
  const size_t NH = (size_t)NSN * 128;
  float* bufS0 = alloc(NH);
  float* bufS1 = alloc(NH);
  float* bufT0 = alloc(NH);
  float* bufT1 = alloc(NH);
  float* sum = alloc(NH);
  float* rc4 = alloc(4 * 50000);
  int* cnt4 = (int*)alloc(4 * 50000);
  float* encTs1 = alloc(64 * 128);
  float* encTs2 = alloc(128 * 128);
  float* encTt1 = alloc(48 * 128);
  float* encTt2 = alloc(128 * 128);
  float* wlT = alloc((size_t)12 * 128 * 128);
  float* wrcT = alloc((size_t)6 * 128 * 128);
  float* blc = alloc(6 * 128);
  float* gw1T = alloc(256 * 128);
  float* mw1T = alloc(160 * 128);
  float* mw2T = alloc(128 * 64);

  // degree counts (constant across layers)
  hipMemsetAsync(cnt4, 0, 4 * 50000 * sizeof(int), stream);
  int cb = (EE + 255) / 256;
  count_k<<<cb, 256, 0, stream>>>(ei_ss + EE, cnt4 + 0 * 50000, EE);
  count_k<<<cb, 256, 0, stream>>>(ei_tt + EE, cnt4 + 1 * 50000, EE);
  count_k<<<cb, 256, 0, stream>>>(ei_st + EE, cnt4 + 2 * 50000, EE);
  count_k<<<cb, 256, 0, stream>>>(ei_ts + EE, cnt4 + 3 * 50000, EE);
  rcnt_k<<<(200000 + 255) / 256, 256, 0, stream>>>(cnt4, rc4, 200000);

  dim3 tb(32, 8);
  transpose_k<<<dim3(2, 4, 1), tb, 0, stream>>>(enc_s_w1, encTs1, 128, 64);
  transpose_k<<<dim3(4, 4, 1), tb, 0, stream>>>(enc_s_w2, encTs2, 128, 128);
  transpose_k<<<dim3(2, 4, 1), tb, 0, stream>>>(enc_t_w1, encTt1, 128, 48);
  transpose_k<<<dim3(4, 4, 1), tb, 0, stream>>>(enc_t_w2, encTt2, 128, 128);
  transpose_k<<<dim3(4, 4, 12), tb, 0, stream>>>(conv_wl, wlT, 128, 128);
  transpose_k<<<dim3(8, 4, 1), tb, 0, stream>>>(gate_w1, gw1T, 128, 256);
  transpose_k<<<dim3(5, 4, 1), tb, 0, stream>>>(mlp_w1, mw1T, 128, 160);
  transpose_k<<<dim3(4, 2, 1), tb, 0, stream>>>(mlp_w2, mw2T, 64, 128);
  combine_wr_k<<<dim3(64, 6), 256, 0, stream>>>(conv_wr, conv_bl, wrcT, blc);

  int gm = (NSN + 127) / 128;
  // encoders (sum used as tmp)
  gemm_k<3><<<gm, 256, 0, stream>>>(x_source, nullptr, encTs1, enc_s_b1, sum, nullptr, NSN, 64);
  gemm_k<0><<<gm, 256, 0, stream>>>(sum, nullptr, encTs2, enc_s_b2, bufS0, nullptr, NSN, 128);
  gemm_k<3><<<gm, 256, 0, stream>>>(x_target, nullptr, encTt1, enc_t_b1, sum, nullptr, NTN, 48);
  gemm_k<0><<<gm, 256, 0, stream>>>(sum, nullptr, encTt2, enc_t_b2, bufT0, nullptr, NTN, 128);

  float* hsA = bufS0; float* hsB = bufS1;
  float* htA = bufT0; float* htB = bufT1;
  int sb = ((size_t)EE * 32 + 255) / 256;
  for (int l = 0; l < 3; ++l) {
    // dst = source : relations ss (wl[l,0]) + ts (wl[l,3])
    hipMemsetAsync(sum, 0, NH * sizeof(float), stream);
    scatter_k<<<sb, 256, 0, stream>>>(hsA, ei_ss, sum, EE);
    gemm_k<0><<<gm, 256, 0, stream>>>(sum, rc4 + 0 * 50000, wlT + (size_t)(l * 4 + 0) * 16384,
                                      blc + (l * 2 + 0) * 128, hsB, nullptr, NSN, 128);
    hipMemsetAsync(sum, 0, NH * sizeof(float), stream);
    scatter_k<<<sb, 256, 0, stream>>>(htA, ei_ts, sum, EE);
    gemm_k<1><<<gm, 256, 0, stream>>>(sum, rc4 + 3 * 50000, wlT + (size_t)(l * 4 + 3) * 16384,
                                      nullptr, hsB, nullptr, NSN, 128);
    gemm_k<2><<<gm, 256, 0, stream>>>(hsA, nullptr, wrcT + (size_t)(l * 2 + 0) * 16384,
                                      nullptr, hsB, l ? hsA : nullptr, NSN, 128);
    // dst = target : relations tt (wl[l,1]) + st (wl[l,2])
    hipMemsetAsync(sum, 0, NH * sizeof(float), stream);
    scatter_k<<<sb, 256, 0, stream>>>(htA, ei_tt, sum, EE);
    gemm_k<0><<<gm, 256, 0, stream>>>(sum, rc4 + 1 * 50000, wlT + (size_t)(l * 4 + 1) * 16384,
                                      blc + (l * 2 + 1) * 128, htB, nullptr, NTN, 128);
    hipMemsetAsync(sum, 0, NH * sizeof(float), stream);
    scatter_k<<<sb, 256, 0, stream>>>(hsA, ei_st, sum, EE);
    gemm_k<1><<<gm, 256, 0, stream>>>(sum, rc4 + 2 * 50000, wlT + (size_t)(l * 4 + 2) * 16384,
                                      nullptr, htB, nullptr, NTN, 128);
    gemm_k<2><<<gm, 256, 0, stream>>>(htA, nullptr, wrcT + (size_t)(l * 2 + 1) * 16384,
                                      nullptr, htB, l ? htA : nullptr, NTN, 128);
    float* tmp = hsA; hsA = hsB; hsB = tmp;
    tmp = htA; htA = htB; htB = tmp;
  }

  edge_head_k<<<EE / 32, 256, 0, stream>>>(hsA, htA, ei_st, edge_attr,
      gw1T, gate_b1, gate_w2, gate_b2, mw1T, mlp_b1, mw2T, mlp_b2, mlp_w3, mlp_b3,
      out, EE);
}

// Round 2
// 4119.918 us; speedup vs baseline: 3.4086x; 3.4086x over previous
//
#include <hip/hip_runtime.h>
#include <cmath>

#define NSN 50000
#define NTN 50000
#define EE  500000

// ---------------------------------------------------------------- transpose
__global__ void transpose_k(const float* __restrict__ src, float* __restrict__ dst,
                            int N, int K) {
  __shared__ float tl[32][33];
  const float* s = src + (size_t)blockIdx.z * N * K;
  float* d = dst + (size_t)blockIdx.z * N * K;
  int x = blockIdx.x * 32 + threadIdx.x;
  int y0 = blockIdx.y * 32;
  for (int i = threadIdx.y; i < 32; i += 8) {
    int y = y0 + i;
    if (y < N && x < K) tl[i][threadIdx.x] = s[(size_t)y * K + x];
  }
  __syncthreads();
  int x2 = y0 + threadIdx.x;
  int yb = blockIdx.x * 32;
  for (int i = threadIdx.y; i < 32; i += 8) {
    int y = yb + i;
    if (y < K && x2 < N) d[(size_t)y * N + x2] = tl[threadIdx.x][i];
  }
}

// ------------------------------------------------- combined wr (+transpose)
__global__ void combine_wr_k(const float* __restrict__ wr, const float* __restrict__ bl,
                             float* __restrict__ wrcT, float* __restrict__ blc) {
  int z = blockIdx.y;
  int l = z >> 1, dd = z & 1;
  int r1 = dd ? 1 : 0, r2 = dd ? 2 : 3;
  int idx = blockIdx.x * 256 + threadIdx.x;
  if (idx < 16384) {
    int k = idx >> 7, n = idx & 127;
    float v = wr[((size_t)(l * 4 + r1) * 128 + n) * 128 + k] +
              wr[((size_t)(l * 4 + r2) * 128 + n) * 128 + k];
    wrcT[(size_t)z * 16384 + idx] = v;
    if (idx < 128) blc[z * 128 + idx] = bl[(l * 4 + r1) * 128 + idx] + bl[(l * 4 + r2) * 128 + idx];
  }
}

// --------------------------------------------------------------- CSR build
__global__ void count_k(const int* __restrict__ col, int* __restrict__ cnt, int E) {
  int i = blockIdx.x * 256 + threadIdx.x;
  if (i < E) atomicAdd(&cnt[col[i]], 1);
}

// one block per relation; chunked shuffle scan
__global__ void scan_k(const int* __restrict__ cnt, int* __restrict__ off,
                       int* __restrict__ cur) {
  __shared__ int wsum[4];
  __shared__ int runS;
  int rel = blockIdx.x;
  const int* c = cnt + (size_t)rel * 50000;
  int* o = off + (size_t)rel * 50001;
  int* cu = cur + (size_t)rel * 50000;
  int t = threadIdx.x, lane = t & 63, w = t >> 6;
  if (t == 0) { runS = 0; o[0] = 0; }
  __syncthreads();
  for (int base = 0; base < 50000; base += 256) {
    int i = base + t;
    int v = (i < 50000) ? c[i] : 0;
    int x = v;
    #pragma unroll
    for (int d = 1; d < 64; d <<= 1) {
      int y = __shfl_up(x, d, 64);
      if (lane >= d) x += y;
    }
    if (lane == 63) wsum[w] = x;
    __syncthreads();
    int add = runS;
    for (int ww = 0; ww < w; ++ww) add += wsum[ww];
    int incl = add + x;
    if (i < 50000) { cu[i] = incl - v; o[i + 1] = incl; }
    __syncthreads();
    if (t == 255) runS = add + x;
    __syncthreads();
  }
}

__global__ void fill_k(const int* __restrict__ ei, int* __restrict__ cur,
                       int* __restrict__ adj, int E) {
  int e = blockIdx.x * 256 + threadIdx.x;
  if (e < E) {
    int colv = ei[E + e], rowv = ei[e];
    int pos = atomicAdd(&cur[colv], 1);
    adj[pos] = rowv;
  }
}

// ------------------------------------------------------------- gather-mean
// one wave per dst node, 4 nodes per block; writes mean directly
__global__ __launch_bounds__(256) void gather_k(const float* __restrict__ src,
    const int* __restrict__ off, const int* __restrict__ adj,
    float* __restrict__ dst, int N) {
  int n = blockIdx.x * 4 + (threadIdx.x >> 6);
  if (n >= N) return;
  int lane = threadIdx.x & 63;
  int s = off[n], eN = off[n + 1];
  float ax = 0.f, ay = 0.f;
  for (int i = s; i < eN; ++i) {
    int r = adj[i];
    const float2 v = *reinterpret_cast<const float2*>(src + (size_t)r * 128 + lane * 2);
    ax += v.x; ay += v.y;
  }
  float inv = 1.f / (float)max(eN - s, 1);
  *reinterpret_cast<float2*>(dst + (size_t)n * 128 + lane * 2) = make_float2(ax * inv, ay * inv);
}

// ------------------------------------------------------------ encoder GEMM
// MODE 0: C = acc + bias   MODE 3: C = relu(acc + bias)
template <int MODE>
__global__ __launch_bounds__(256) void gemm_k(
    const float* __restrict__ A, const float* __restrict__ WT,
    const float* __restrict__ bias, float* __restrict__ C, int M, int K) {
  __shared__ float As[32][132];
  __shared__ float Ws[32][132];
  int m0 = blockIdx.x * 128;
  int t = threadIdx.x;
  int tx = t & 15, ty = t >> 4;
  float acc[8][8] = {};
  for (int kb = 0; kb < K; kb += 32) {
    {
      int k = t & 31, mr = t >> 5;
      int gk = kb + k;
      #pragma unroll
      for (int m = mr; m < 128; m += 8) {
        int gm = m0 + m;
        As[k][m] = (gm < M && gk < K) ? A[(size_t)gm * K + gk] : 0.f;
      }
    }
    {
      int n = t & 127, kk = t >> 7;
      #pragma unroll
      for (int k2 = kk; k2 < 32; k2 += 2) {
        int gk = kb + k2;
        Ws[k2][n] = (gk < K) ? WT[(size_t)gk * 128 + n] : 0.f;
      }
    }
    __syncthreads();
    #pragma unroll
    for (int k = 0; k < 32; ++k) {
      float a[8], b[8];
      *(float4*)&a[0] = *(const float4*)&As[k][ty * 8];
      *(float4*)&a[4] = *(const float4*)&As[k][ty * 8 + 4];
      *(float4*)&b[0] = *(const float4*)&Ws[k][tx * 8];
      *(float4*)&b[4] = *(const float4*)&Ws[k][tx * 8 + 4];
      #pragma unroll
      for (int i = 0; i < 8; ++i)
        #pragma unroll
        for (int j = 0; j < 8; ++j) acc[i][j] = fmaf(a[i], b[j], acc[i][j]);
    }
    __syncthreads();
  }
  #pragma unroll
  for (int i = 0; i < 8; ++i) {
    int gm = m0 + ty * 8 + i;
    if (gm >= M) continue;
    float* cp = C + (size_t)gm * 128 + tx * 8;
    float o[8];
    #pragma unroll
    for (int j = 0; j < 8; ++j) {
      float v = acc[i][j] + bias[tx * 8 + j];
      if (MODE == 3) v = fmaxf(v, 0.f);
      o[j] = v;
    }
    *(float4*)cp = make_float4(o[0], o[1], o[2], o[3]);
    *(float4*)(cp + 4) = make_float4(o[4], o[5], o[6], o[7]);
  }
}

// ----------------------------------------------------- fused 3-way layer GEMM
// C = relu(0.5*(A0@W0 + A1@W1 + A2@W2 + bias) + res)    (64x128 tile)
template <int RES>
__global__ __launch_bounds__(256) void gemm3_k(
    const float* __restrict__ A0, const float* __restrict__ A1, const float* __restrict__ A2,
    const float* __restrict__ W0, const float* __restrict__ W1, const float* __restrict__ W2,
    const float* __restrict__ bias, float* __restrict__ C,
    const float* __restrict__ res, int M) {
  __shared__ float As[32][68];
  __shared__ float Ws[32][132];
  int m0 = blockIdx.x * 64;
  int t = threadIdx.x;
  int tx = t & 15, ty = t >> 4;
  float acc[4][8] = {};
  #pragma unroll
  for (int p = 0; p < 3; ++p) {
    const float* A = p == 0 ? A0 : (p == 1 ? A1 : A2);
    const float* WT = p == 0 ? W0 : (p == 1 ? W1 : W2);
    for (int kb = 0; kb < 128; kb += 32) {
      {
        int k = t & 31, mr = t >> 5;
        #pragma unroll
        for (int m = mr; m < 64; m += 8) {
          int gm = m0 + m;
          As[k][m] = (gm < M) ? A[(size_t)gm * 128 + kb + k] : 0.f;
        }
      }
      {
        int n = t & 127, kk = t >> 7;
        #pragma unroll
        for (int k2 = kk; k2 < 32; k2 += 2)
          Ws[k2][n] = WT[(size_t)(kb + k2) * 128 + n];
      }
      __syncthreads();
      #pragma unroll
      for (int k3 = 0; k3 < 32; ++k3) {
        float a[4], b[8];
        *(float4*)&a[0] = *(const float4*)&As[k3][ty * 4];
        *(float4*)&b[0] = *(const float4*)&Ws[k3][tx * 8];
        *(float4*)&b[4] = *(const float4*)&Ws[k3][tx * 8 + 4];
        #pragma unroll
        for (int i = 0; i < 4; ++i)
          #pragma unroll
          for (int j = 0; j < 8; ++j) acc[i][j] = fmaf(a[i], b[j], acc[i][j]);
      }
      __syncthreads();
    }
  }
  #pragma unroll
  for (int i = 0; i < 4; ++i) {
    int gm = m0 + ty * 4 + i;
    if (gm >= M) continue;
    float* cp = C + (size_t)gm * 128 + tx * 8;
    const float* rp = RES ? res + (size_t)gm * 128 + tx * 8 : nullptr;
    float o[8];
    #pragma unroll
    for (int j = 0; j < 8; ++j) {
      float v = 0.5f * (acc[i][j] + bias[tx * 8 + j]);
      if (RES) v += rp[j];
      o[j] = fmaxf(v, 0.f);
    }
    *(float4*)cp = make_float4(o[0], o[1], o[2], o[3]);
    *(float4*)(cp + 4) = make_float4(o[4], o[5], o[6], o[7]);
  }
}

// ---------------------------------------------------------------- edge head
#define CST 34
__global__ __launch_bounds__(256) void edge_head_k(
    const float* __restrict__ hs, const float* __restrict__ ht,
    const int* __restrict__ ei, const float* __restrict__ ea,
    const float* __restrict__ gw1T, const float* __restrict__ gb1,
    const float* __restrict__ gw2, const float* __restrict__ gb2,
    const float* __restrict__ mw1T, const float* __restrict__ mb1,
    const float* __restrict__ mw2T, const float* __restrict__ mb2,
    const float* __restrict__ mw3, const float* __restrict__ mb3,
    float* __restrict__ out, int Etot) {
  __shared__ float smem[(256 + 128) * CST];
  float (*catT)[CST] = (float(*)[CST])smem;               // 256 rows
  float (*h1T)[CST] = (float(*)[CST])(smem + 256 * CST);  // 128 rows
  float (*h2T)[CST] = (float(*)[CST])smem;                // 64 rows, aliases catT (dead after P4)
  __shared__ float gbuf[32];
  __shared__ int eidx[64];
  int t = threadIdx.x;
  int e0 = blockIdx.x * 32;
  if (t < 32) eidx[t] = ei[e0 + t];
  else if (t < 64) eidx[t] = ei[Etot + e0 + (t - 32)];
  __syncthreads();
  // P0: stage cat = [src_h | tgt_h]
  for (int i = t; i < 32 * 128; i += 256) {
    int e = i >> 7, c = i & 127;
    catT[c][e] = hs[(size_t)eidx[e] * 128 + c];
    catT[128 + c][e] = ht[(size_t)eidx[32 + e] * 128 + c];
  }
  __syncthreads();
  int tx = t & 15, ty = t >> 4;   // j = tx*8.., e = ty*2..
  // P1: gate hidden (K=256)
  {
    float acc0[8] = {}, acc1[8] = {};
    #pragma unroll 4
    for (int k = 0; k < 256; ++k) {
      float2 a = *(const float2*)&catT[k][ty * 2];
      float4 w0 = __ldg((const float4*)(gw1T + (size_t)k * 128 + tx * 8));
      float4 w1 = __ldg((const float4*)(gw1T + (size_t)k * 128 + tx * 8 + 4));
      float wv[8] = {w0.x, w0.y, w0.z, w0.w, w1.x, w1.y, w1.z, w1.w};
      #pragma unroll
      for (int j = 0; j < 8; ++j) {
        acc0[j] = fmaf(a.x, wv[j], acc0[j]);
        acc1[j] = fmaf(a.y, wv[j], acc1[j]);
      }
    }
    #pragma unroll
    for (int j = 0; j < 8; ++j) {
      float b = gb1[tx * 8 + j];
      h1T[tx * 8 + j][ty * 2] = fmaxf(acc0[j] + b, 0.f);
      h1T[tx * 8 + j][ty * 2 + 1] = fmaxf(acc1[j] + b, 0.f);
    }
  }
  __syncthreads();
  // P2: gate scalar
  {
    int e = t >> 3, jl = t & 7;
    float s = 0.f;
    for (int j = jl; j < 128; j += 8) s += gw2[j] * h1T[j][e];
    s += __shfl_xor(s, 1, 64); s += __shfl_xor(s, 2, 64); s += __shfl_xor(s, 4, 64);
    if (jl == 0) gbuf[e] = 1.f / (1.f + expf(-(s + gb2[0])));
  }
  __syncthreads();
  // P3: combined -> catT[0..127], edge_attr -> catT[128..159]
  for (int i = t; i < 32 * 128; i += 256) {
    int e = i >> 7, c = i & 127;
    float g = gbuf[e];
    catT[c][e] = catT[c][e] * g + catT[128 + c][e] * (1.f - g);
  }
  __syncthreads();
  for (int i = t; i < 32 * 32; i += 256) {
    int e = i >> 5, c = i & 31;
    catT[128 + c][e] = ea[(size_t)(e0 + e) * 32 + c];
  }
  __syncthreads();
  // P4: mlp layer1 (K=160) -> h1T
  {
    float acc0[8] = {}, acc1[8] = {};
    #pragma unroll 4
    for (int k = 0; k < 160; ++k) {
      float2 a = *(const float2*)&catT[k][ty * 2];
      float4 w0 = __ldg((const float4*)(mw1T + (size_t)k * 128 + tx * 8));
      float4 w1 = __ldg((const float4*)(mw1T + (size_t)k * 128 + tx * 8 + 4));
      float wv[8] = {w0.x, w0.y, w0.z, w0.w, w1.x, w1.y, w1.z, w1.w};
      #pragma unroll
      for (int j = 0; j < 8; ++j) {
        acc0[j] = fmaf(a.x, wv[j], acc0[j]);
        acc1[j] = fmaf(a.y, wv[j], acc1[j]);
      }
    }
    #pragma unroll
    for (int j = 0; j < 8; ++j) {
      float b = mb1[tx * 8 + j];
      h1T[tx * 8 + j][ty * 2] = fmaxf(acc0[j] + b, 0.f);
      h1T[tx * 8 + j][ty * 2 + 1] = fmaxf(acc1[j] + b, 0.f);
    }
  }
  __syncthreads();
  // P5: mlp layer2 (K=128, N=64) -> h2T (aliases catT region)
  {
    int tx2 = t & 7, ty2 = t >> 3;
    float acc[8] = {};
    #pragma unroll 4
    for (int k = 0; k < 128; ++k) {
      float a = h1T[k][ty2];
      float4 w0 = __ldg((const float4*)(mw2T + (size_t)k * 64 + tx2 * 8));
      float4 w1 = __ldg((const float4*)(mw2T + (size_t)k * 64 + tx2 * 8 + 4));
      float wv[8] = {w0.x, w0.y, w0.z, w0.w, w1.x, w1.y, w1.z, w1.w};
      #pragma unroll
      for (int j = 0; j < 8; ++j) acc[j] = fmaf(a, wv[j], acc[j]);
    }
    #pragma unroll
    for (int j = 0; j < 8; ++j)
      h2T[tx2 * 8 + j][ty2] = fmaxf(acc[j] + mb2[tx2 * 8 + j], 0.f);
  }
  __syncthreads();
  // P6: output (K=64, N=2)
  if (t < 64) {
    int e = t & 31, o = t >> 5;
    float s = mb3[o];
    for (int k = 0; k < 64; ++k) s += h2T[k][e] * mw3[o * 64 + k];
    out[(size_t)(e0 + e) * 2 + o] = s;
  }
}

// ------------------------------------------------------------------- launch
extern "C" void kernel_launch(void* const* d_in, const int* in_sizes, int n_in,
                              void* d_out, int out_size, void* d_ws, size_t ws_size,
                              hipStream_t stream) {
  const float* x_source = (const float*)d_in[0];
  const float* x_target = (const float*)d_in[1];
  const float* edge_attr = (const float*)d_in[2];
  const float* enc_s_w1 = (const float*)d_in[3];
  const float* enc_s_b1 = (const float*)d_in[4];
  const float* enc_s_w2 = (const float*)d_in[5];
  const float* enc_s_b2 = (const float*)d_in[6];
  const float* enc_t_w1 = (const float*)d_in[7];
  const float* enc_t_b1 = (const float*)d_in[8];
  const float* enc_t_w2 = (const float*)d_in[9];
  const float* enc_t_b2 = (const float*)d_in[10];
  const float* conv_wl = (const float*)d_in[11];
  const float* conv_bl = (const float*)d_in[12];
  const float* conv_wr = (const float*)d_in[13];
  const float* gate_w1 = (const float*)d_in[14];
  const float* gate_b1 = (const float*)d_in[15];
  const float* gate_w2 = (const float*)d_in[16];
  const float* gate_b2 = (const float*)d_in[17];
  const float* mlp_w1 = (const float*)d_in[18];
  const float* mlp_b1 = (const float*)d_in[19];
  const float* mlp_w2 = (const float*)d_in[20];
  const float* mlp_b2 = (const float*)d_in[21];
  const float* mlp_w3 = (const float*)d_in[22];
  const float* mlp_b3 = (const float*)d_in[23];
  const int* ei[4] = {(const int*)d_in[24], (const int*)d_in[25],
                      (const int*)d_in[26], (const int*)d_in[27]};  // 0=ss,1=tt,2=st,3=ts

  float* out = (float*)d_out;
  float* w = (float*)d_ws;
  size_t off = 0;
  auto alloc = [&](size_t n) { float* p = w + off; off += n; return p; };
  const size_t NH = (size_t)NSN * 128;
  float* B[5];
  for (int i = 0; i < 5; ++i) B[i] = alloc(NH);
  int* adj4 = (int*)alloc((size_t)4 * EE);
  int* off4 = (int*)alloc(4 * 50001 + 4);
  int* cur4 = (int*)alloc(4 * 50000);
  int* cnt4 = (int*)alloc(4 * 50000);
  float* encTs1 = alloc(64 * 128);
  float* encTs2 = alloc(128 * 128);
  float* encTt1 = alloc(48 * 128);
  float* encTt2 = alloc(128 * 128);
  float* wlT = alloc((size_t)12 * 16384);
  float* wrcT = alloc((size_t)6 * 16384);
  float* blc = alloc(6 * 128);
  float* gw1T = alloc(256 * 128);
  float* mw1T = alloc(160 * 128);
  float* mw2T = alloc(128 * 64);

  // --- CSR build (col-indexed, values = src rows) ---
  hipMemsetAsync(cnt4, 0, 4 * 50000 * sizeof(int), stream);
  int cb = (EE + 255) / 256;
  for (int r = 0; r < 4; ++r)
    count_k<<<cb, 256, 0, stream>>>(ei[r] + EE, cnt4 + (size_t)r * 50000, EE);
  scan_k<<<4, 256, 0, stream>>>(cnt4, off4, cur4);
  for (int r = 0; r < 4; ++r)
    fill_k<<<cb, 256, 0, stream>>>(ei[r], cur4 + (size_t)r * 50000,
                                   adj4 + (size_t)r * EE, EE);

  // --- weight prep ---
  dim3 tb(32, 8);
  transpose_k<<<dim3(2, 4, 1), tb, 0, stream>>>(enc_s_w1, encTs1, 128, 64);
  transpose_k<<<dim3(4, 4, 1), tb, 0, stream>>>(enc_s_w2, encTs2, 128, 128);
  transpose_k<<<dim3(2, 4, 1), tb, 0, stream>>>(enc_t_w1, encTt1, 128, 48);
  transpose_k<<<dim3(4, 4, 1), tb, 0, stream>>>(enc_t_w2, encTt2, 128, 128);
  transpose_k<<<dim3(4, 4, 12), tb, 0, stream>>>(conv_wl, wlT, 128, 128);
  transpose_k<<<dim3(8, 4, 1), tb, 0, stream>>>(gate_w1, gw1T, 128, 256);
  transpose_k<<<dim3(5, 4, 1), tb, 0, stream>>>(mlp_w1, mw1T, 128, 160);
  transpose_k<<<dim3(4, 2, 1), tb, 0, stream>>>(mlp_w2, mw2T, 64, 128);
  combine_wr_k<<<dim3(64, 6), 256, 0, stream>>>(conv_wr, conv_bl, wrcT, blc);

  // --- encoders (B[2] as tmp) ---
  int gm = (NSN + 127) / 128;
  gemm_k<3><<<gm, 256, 0, stream>>>(x_source, encTs1, enc_s_b1, B[2], NSN, 64);
  gemm_k<0><<<gm, 256, 0, stream>>>(B[2], encTs2, enc_s_b2, B[0], NSN, 128);
  gemm_k<3><<<gm, 256, 0, stream>>>(x_target, encTt1, enc_t_b1, B[2], NTN, 48);
  gemm_k<0><<<gm, 256, 0, stream>>>(B[2], encTt2, enc_t_b2, B[1], NTN, 128);

  float* hs = B[0]; float* ht = B[1];
  float* f0 = B[2]; float* f1 = B[3]; float* f2 = B[4];
  int gb = (NSN + 3) / 4;
  int g3 = (NSN + 63) / 64;
  for (int l = 0; l < 3; ++l) {
    const float* wl0 = wlT + (size_t)(l * 4 + 0) * 16384;
    const float* wl1 = wlT + (size_t)(l * 4 + 1) * 16384;
    const float* wl2 = wlT + (size_t)(l * 4 + 2) * 16384;
    const float* wl3 = wlT + (size_t)(l * 4 + 3) * 16384;
    // dst = source: aggSS(hs via ss) -> f0, aggTS(ht via ts) -> f1
    gather_k<<<gb, 256, 0, stream>>>(hs, off4 + 0 * 50001, adj4 + (size_t)0 * EE, f0, NSN);
    gather_k<<<gb, 256, 0, stream>>>(ht, off4 + 3 * 50001, adj4 + (size_t)3 * EE, f1, NSN);
    if (l == 0)
      gemm3_k<0><<<g3, 256, 0, stream>>>(f0, f1, hs, wl0, wl3,
          wrcT + (size_t)(l * 2 + 0) * 16384, blc + (l * 2 + 0) * 128, f0, nullptr, NSN);
    else
      gemm3_k<1><<<g3, 256, 0, stream>>>(f0, f1, hs, wl0, wl3,
          wrcT + (size_t)(l * 2 + 0) * 16384, blc + (l * 2 + 0) * 128, f0, hs, NSN);
    // dst = target: aggTT(ht via tt) -> f1 (reuse), aggST(hs_old via st) -> f2
    gather_k<<<gb, 256, 0, stream>>>(ht, off4 + 1 * 50001, adj4 + (size_t)1 * EE, f1, NTN);
    gather_k<<<gb, 256, 0, stream>>>(hs, off4 + 2 * 50001, adj4 + (size_t)2 * EE, f2, NTN);
    if (l == 0)
      gemm3_k<0><<<g3, 256, 0, stream>>>(f1, f2, ht, wl1, wl2,
          wrcT + (size_t)(l * 2 + 1) * 16384, blc + (l * 2 + 1) * 128, f1, nullptr, NTN);
    else
      gemm3_k<1><<<g3, 256, 0, stream>>>(f1, f2, ht, wl1, wl2,
          wrcT + (size_t)(l * 2 + 1) * 16384, blc + (l * 2 + 1) * 128, f1, ht, NTN);
    // rotate: new hs=f0, new ht=f1; freed: old hs, old ht (f2 stays scratch)
    float* nhs = f0; float* nht = f1;
    f0 = hs; f1 = ht;
    hs = nhs; ht = nht;
  }

  edge_head_k<<<EE / 32, 256, 0, stream>>>(hs, ht, ei[2], edge_attr,
      gw1T, gate_b1, gate_w2, gate_b2, mw1T, mlp_b1, mw2T, mlp_b2, mlp_w3, mlp_b3,
      out, EE);
}

// Round 3
// 1186.741 us; speedup vs baseline: 11.8333x; 3.4716x over previous
//
#include <hip/hip_runtime.h>
#include <cmath>

#define NSN 50000
#define NTN 50000
#define EE  500000

using short8 = __attribute__((ext_vector_type(8))) short;
using f32x4  = __attribute__((ext_vector_type(4))) float;
#define MFMA16(a, b, c) __builtin_amdgcn_mfma_f32_16x16x32_bf16(a, b, c, 0, 0, 0)

__device__ __forceinline__ float  b2f(ushort u) { return __uint_as_float(((uint)u) << 16); }
__device__ __forceinline__ ushort f2b(float f) {
  uint x = __float_as_uint(f);
  uint r = x + 0x7FFFu + ((x >> 16) & 1u);
  return (ushort)(r >> 16);
}
__device__ __forceinline__ float blo(uint x) { return __uint_as_float(x << 16); }
__device__ __forceinline__ float bhi(uint x) { return __uint_as_float(x & 0xFFFF0000u); }
__device__ __forceinline__ uint  pk2(float a, float b) { return (uint)f2b(a) | ((uint)f2b(b) << 16); }

// ------------------------------------------------------------- conversions
__global__ void cvt_k(const float* __restrict__ s, ushort* __restrict__ d, int n) {
  int i = blockIdx.x * 256 + threadIdx.x;
  if (i < n) d[i] = f2b(s[i]);
}
// pad columns SK -> 64 (zero fill)
__global__ void pad_cvt_k(const float* __restrict__ s, ushort* __restrict__ d,
                          int rows, int SK) {
  int i = blockIdx.x * 256 + threadIdx.x;
  if (i < rows * 64) {
    int r = i >> 6, k = i & 63;
    d[i] = (k < SK) ? f2b(s[(size_t)r * SK + k]) : (ushort)0;
  }
}
// combined wr (native [N][K] layout, no transpose) + combined bias (fp32)
__global__ void wrc_k(const float* __restrict__ wr, const float* __restrict__ bl,
                      ushort* __restrict__ wrcB, float* __restrict__ blc) {
  int z = blockIdx.y;
  int l = z >> 1, dd = z & 1;
  int r1 = dd ? 1 : 0, r2 = dd ? 2 : 3;
  int idx = blockIdx.x * 256 + threadIdx.x;
  if (idx < 16384) {
    wrcB[(size_t)z * 16384 + idx] =
        f2b(wr[(size_t)(l * 4 + r1) * 16384 + idx] + wr[(size_t)(l * 4 + r2) * 16384 + idx]);
    if (idx < 128)
      blc[z * 128 + idx] = bl[(l * 4 + r1) * 128 + idx] + bl[(l * 4 + r2) * 128 + idx];
  }
}
// head weight assembly: PSg, PTg (gw1 halves), WcB (mw1 first 128), w1eB, w2B
__global__ void headw_k(const float* __restrict__ gw1, const float* __restrict__ mw1,
                        const float* __restrict__ mw2,
                        ushort* __restrict__ PSg, ushort* __restrict__ PTg,
                        ushort* __restrict__ WcB, ushort* __restrict__ w1eB,
                        ushort* __restrict__ w2B) {
  int idx = blockIdx.x * 256 + threadIdx.x;
  if (idx < 16384) {
    PSg[idx] = f2b(gw1[(size_t)(idx >> 7) * 256 + (idx & 127)]);
  } else if (idx < 32768) {
    int i = idx - 16384;
    PTg[i] = f2b(gw1[(size_t)(i >> 7) * 256 + 128 + (i & 127)]);
  } else if (idx < 49152) {
    int i = idx - 32768;
    WcB[i] = f2b(mw1[(size_t)(i >> 7) * 160 + (i & 127)]);
  } else if (idx < 53248) {
    int i = idx - 49152;
    w1eB[i] = f2b(mw1[(size_t)(i >> 5) * 160 + 128 + (i & 31)]);
  } else if (idx < 61440) {
    int i = idx - 53248;
    w2B[i] = f2b(mw2[i]);
  }
}

// --------------------------------------------------------------- CSR build
__global__ void count_k(const int* __restrict__ col, int* __restrict__ cnt, int E) {
  int i = blockIdx.x * 256 + threadIdx.x;
  if (i < E) atomicAdd(&cnt[col[i]], 1);
}
__global__ void scan_k(const int* __restrict__ cnt, int* __restrict__ off,
                       int* __restrict__ cur) {
  __shared__ int wsum[4];
  __shared__ int runS;
  int rel = blockIdx.x;
  const int* c = cnt + (size_t)rel * 50000;
  int* o = off + (size_t)rel * 50001;
  int* cu = cur + (size_t)rel * 50000;
  int t = threadIdx.x, lane = t & 63, w = t >> 6;
  if (t == 0) { runS = 0; o[0] = 0; }
  __syncthreads();
  for (int base = 0; base < 50000; base += 256) {
    int i = base + t;
    int v = (i < 50000) ? c[i] : 0;
    int x = v;
    #pragma unroll
    for (int d = 1; d < 64; d <<= 1) {
      int y = __shfl_up(x, d, 64);
      if (lane >= d) x += y;
    }
    if (lane == 63) wsum[w] = x;
    __syncthreads();
    int add = runS;
    for (int ww = 0; ww < w; ++ww) add += wsum[ww];
    int incl = add + x;
    if (i < 50000) { cu[i] = incl - v; o[i + 1] = incl; }
    __syncthreads();
    if (t == 255) runS = add + x;
    __syncthreads();
  }
}
__global__ void fill_k(const int* __restrict__ ei, int* __restrict__ cur,
                       int* __restrict__ adj, int E) {
  int e = blockIdx.x * 256 + threadIdx.x;
  if (e < E) {
    int pos = atomicAdd(&cur[ei[E + e]], 1);
    adj[pos] = ei[e];
  }
}

// ------------------------------------------------------------- gather-mean
// 2 nodes per wave, 8 per block; bf16 in/out, fp32 accumulate
__global__ __launch_bounds__(256) void gather_k(const ushort* __restrict__ src,
    const int* __restrict__ off, const int* __restrict__ adj,
    ushort* __restrict__ dst, int N) {
  int lane = threadIdx.x & 63;
  int n = blockIdx.x * 8 + (threadIdx.x >> 6) * 2 + (lane >> 5);
  if (n >= N) return;
  int l32 = lane & 31;
  int s = off[n], e = off[n + 1];
  float a0 = 0.f, a1 = 0.f, a2 = 0.f, a3 = 0.f;
  for (int i = s; i < e; ++i) {
    int r = adj[i];
    ushort4 v = *reinterpret_cast<const ushort4*>(src + (size_t)r * 128 + l32 * 4);
    a0 += b2f(v.x); a1 += b2f(v.y); a2 += b2f(v.z); a3 += b2f(v.w);
  }
  float inv = 1.f / (float)max(e - s, 1);
  ushort4 o;
  o.x = f2b(a0 * inv); o.y = f2b(a1 * inv); o.z = f2b(a2 * inv); o.w = f2b(a3 * inv);
  *reinterpret_cast<ushort4*>(dst + (size_t)n * 128 + l32 * 4) = o;
}

// ------------------------------------------------------- MFMA GEMM (N=128)
// C[M][128] = op(A[M][K] @ W[128][K]^T); A,W bf16, acc fp32, out bf16
// MODE 0: acc + bias(optional)    MODE 1: relu(acc + bias)
template <int MODE>
__global__ __launch_bounds__(256) void gemmN_k(
    const ushort* __restrict__ A, const ushort* __restrict__ W,
    const float* __restrict__ bias, ushort* __restrict__ C, int M, int K, int ldc) {
  __shared__ alignas(16) ushort As[128][40];
  __shared__ alignas(16) ushort Ws[128][40];
  int t = threadIdx.x;
  int m0 = blockIdx.x * 128;
  int lane = t & 63, w = t >> 6, wm = w >> 1, wn = w & 1;
  f32x4 zz = {0.f, 0.f, 0.f, 0.f};
  f32x4 acc[4][4];
  #pragma unroll
  for (int i = 0; i < 4; ++i)
    #pragma unroll
    for (int j = 0; j < 4; ++j) acc[i][j] = zz;
  for (int kb = 0; kb < K; kb += 32) {
    #pragma unroll
    for (int s = 0; s < 2; ++s) {
      int idx = t + s * 256;
      int r = idx >> 2, c = idx & 3;
      int gm = m0 + r;
      uint4 va = make_uint4(0, 0, 0, 0);
      if (gm < M) va = *(const uint4*)(A + (size_t)gm * K + kb + c * 8);
      *(uint4*)&As[r][c * 8] = va;
      *(uint4*)&Ws[r][c * 8] = *(const uint4*)(W + (size_t)r * K + kb + c * 8);
    }
    __syncthreads();
    short8 af[4], bf[4];
    #pragma unroll
    for (int mf = 0; mf < 4; ++mf)
      af[mf] = *(const short8*)&As[wm * 64 + mf * 16 + (lane & 15)][(lane >> 4) * 8];
    #pragma unroll
    for (int nf = 0; nf < 4; ++nf)
      bf[nf] = *(const short8*)&Ws[wn * 64 + nf * 16 + (lane & 15)][(lane >> 4) * 8];
    #pragma unroll
    for (int mf = 0; mf < 4; ++mf)
      #pragma unroll
      for (int nf = 0; nf < 4; ++nf) acc[mf][nf] = MFMA16(af[mf], bf[nf], acc[mf][nf]);
    __syncthreads();
  }
  int r0 = (lane >> 4) * 4, nin = lane & 15;
  #pragma unroll
  for (int mf = 0; mf < 4; ++mf)
    #pragma unroll
    for (int nf = 0; nf < 4; ++nf) {
      int n = wn * 64 + nf * 16 + nin;
      float bv = bias ? bias[n] : 0.f;
      #pragma unroll
      for (int i = 0; i < 4; ++i) {
        int gm = m0 + wm * 64 + mf * 16 + r0 + i;
        if (gm >= M) continue;
        float v = acc[mf][nf][i] + bv;
        if (MODE == 1) v = fmaxf(v, 0.f);
        C[(size_t)gm * ldc + n] = f2b(v);
      }
    }
}

// --------------------------------------- fused 3-input layer GEMM (K=3x128)
// C = relu(0.5*(A0@W0^T + A1@W1^T + A2@W2^T + bias) [+ res]); all bf16
template <int RES>
__global__ __launch_bounds__(256) void gemm3_k(
    const ushort* __restrict__ A0, const ushort* __restrict__ A1, const ushort* __restrict__ A2,
    const ushort* __restrict__ W0, const ushort* __restrict__ W1, const ushort* __restrict__ W2,
    const float* __restrict__ bias, const ushort* __restrict__ res,
    ushort* __restrict__ C, int M) {
  __shared__ alignas(16) ushort As[128][40];
  __shared__ alignas(16) ushort Ws[128][40];
  int t = threadIdx.x;
  int m0 = blockIdx.x * 128;
  int lane = t & 63, w = t >> 6, wm = w >> 1, wn = w & 1;
  f32x4 zz = {0.f, 0.f, 0.f, 0.f};
  f32x4 acc[4][4];
  #pragma unroll
  for (int i = 0; i < 4; ++i)
    #pragma unroll
    for (int j = 0; j < 4; ++j) acc[i][j] = zz;
  for (int p = 0; p < 3; ++p) {
    const ushort* A = p == 0 ? A0 : (p == 1 ? A1 : A2);
    const ushort* W = p == 0 ? W0 : (p == 1 ? W1 : W2);
    for (int kb = 0; kb < 128; kb += 32) {
      #pragma unroll
      for (int s = 0; s < 2; ++s) {
        int idx = t + s * 256;
        int r = idx >> 2, c = idx & 3;
        int gm = m0 + r;
        uint4 va = make_uint4(0, 0, 0, 0);
        if (gm < M) va = *(const uint4*)(A + (size_t)gm * 128 + kb + c * 8);
        *(uint4*)&As[r][c * 8] = va;
        *(uint4*)&Ws[r][c * 8] = *(const uint4*)(W + (size_t)r * 128 + kb + c * 8);
      }
      __syncthreads();
      short8 af[4], bf[4];
      #pragma unroll
      for (int mf = 0; mf < 4; ++mf)
        af[mf] = *(const short8*)&As[wm * 64 + mf * 16 + (lane & 15)][(lane >> 4) * 8];
      #pragma unroll
      for (int nf = 0; nf < 4; ++nf)
        bf[nf] = *(const short8*)&Ws[wn * 64 + nf * 16 + (lane & 15)][(lane >> 4) * 8];
      #pragma unroll
      for (int mf = 0; mf < 4; ++mf)
        #pragma unroll
        for (int nf = 0; nf < 4; ++nf) acc[mf][nf] = MFMA16(af[mf], bf[nf], acc[mf][nf]);
      __syncthreads();
    }
  }
  int r0 = (lane >> 4) * 4, nin = lane & 15;
  #pragma unroll
  for (int mf = 0; mf < 4; ++mf)
    #pragma unroll
    for (int nf = 0; nf < 4; ++nf) {
      int n = wn * 64 + nf * 16 + nin;
      float bv = bias[n];
      #pragma unroll
      for (int i = 0; i < 4; ++i) {
        int gm = m0 + wm * 64 + mf * 16 + r0 + i;
        if (gm >= M) continue;
        float v = 0.5f * (acc[mf][nf][i] + bv);
        if (RES) v += b2f(res[(size_t)gm * 128 + n]);
        C[(size_t)gm * 128 + n] = f2b(fmaxf(v, 0.f));
      }
    }
}

// ---------------------------------------------------------------- edge head
// per 64-edge block: gate from nodewise precomps + ea MFMA + h2 MFMA + out
__global__ __launch_bounds__(256) void head_k(
    const ushort* __restrict__ pS, const ushort* __restrict__ pT,  // [N][256]: [gate|u']
    const int* __restrict__ ei, const float* __restrict__ ea,
    const ushort* __restrict__ w1eB, const ushort* __restrict__ w2B,
    const float* __restrict__ gw2, const float* __restrict__ gb2p,
    const float* __restrict__ mb2, const float* __restrict__ mw3,
    const float* __restrict__ mb3, float* __restrict__ out, int E) {
  __shared__ alignas(16) ushort eatB[64][136];   // eat (bf16); aliased by h2F after
  __shared__ alignas(16) ushort h1s[64][136];
  __shared__ alignas(16) ushort eaS[64][40];
  __shared__ int er[64], ec[64];
  __shared__ alignas(16) float gw2s[128];
  __shared__ alignas(16) float mw3s[128];
  __shared__ float mb2s[64];
  float (*h2F)[68] = (float(*)[68])&eatB[0][0];  // 64x68 f32 == 64x136 ush

  int t = threadIdx.x;
  int e0 = blockIdx.x * 64;
  if (t < 64) {
    int eg = e0 + t;
    er[t] = (eg < E) ? ei[eg] : 0;
    mb2s[t] = mb2[t];
  } else if (t < 128) {
    int q = t - 64;
    int eg = e0 + q;
    ec[q] = (eg < E) ? ei[E + eg] : 0;
  }
  if (t < 128) gw2s[t] = gw2[t];
  else mw3s[t - 128] = mw3[t - 128];
  // stage ea -> bf16 LDS
  {
    int i0 = t * 8;
    int e = i0 >> 5, c = i0 & 31;
    int eg = e0 + e;
    float4 f0 = make_float4(0, 0, 0, 0), f1 = make_float4(0, 0, 0, 0);
    if (eg < E) {
      f0 = *(const float4*)(ea + (size_t)eg * 32 + c);
      f1 = *(const float4*)(ea + (size_t)eg * 32 + c + 4);
    }
    uint4 pkd = make_uint4(pk2(f0.x, f0.y), pk2(f0.z, f0.w), pk2(f1.x, f1.y), pk2(f1.z, f1.w));
    *(uint4*)&eaS[e][c] = pkd;
  }
  __syncthreads();
  int lane = t & 63, w = t >> 6;
  // Phase E: eat = ea @ w1e^T  (M=64, N=128, K=32) via MFMA
  {
    short8 a = *(const short8*)&eaS[w * 16 + (lane & 15)][(lane >> 4) * 8];
    int ebase = w * 16 + (lane >> 4) * 4;
    #pragma unroll
    for (int nf = 0; nf < 8; ++nf) {
      short8 b = *(const short8*)(w1eB + (size_t)(nf * 16 + (lane & 15)) * 32 + (lane >> 4) * 8);
      f32x4 cz = {0.f, 0.f, 0.f, 0.f};
      cz = MFMA16(a, b, cz);
      int jj = nf * 16 + (lane & 15);
      #pragma unroll
      for (int i = 0; i < 4; ++i) eatB[ebase + i][jj] = f2b(cz[i]);
    }
  }
  __syncthreads();
  // Phase G: gate + combine -> h1 (bf16 LDS)
  {
    int el = lane >> 2, q = lane & 3, e = w * 16 + el;
    int j0 = q * 32;
    const ushort* ps = pS + (size_t)er[e] * 256;
    const ushort* pt = pT + (size_t)ec[e] * 256;
    float dot = 0.f;
    #pragma unroll
    for (int cc = 0; cc < 4; ++cc) {
      int j = j0 + cc * 8;
      uint4 ga = *(const uint4*)(ps + j);
      uint4 gb = *(const uint4*)(pt + j);
      const float* gp = &gw2s[j];
      float h;
      h = fmaxf(blo(ga.x) + blo(gb.x), 0.f); dot = fmaf(h, gp[0], dot);
      h = fmaxf(bhi(ga.x) + bhi(gb.x), 0.f); dot = fmaf(h, gp[1], dot);
      h = fmaxf(blo(ga.y) + blo(gb.y), 0.f); dot = fmaf(h, gp[2], dot);
      h = fmaxf(bhi(ga.y) + bhi(gb.y), 0.f); dot = fmaf(h, gp[3], dot);
      h = fmaxf(blo(ga.z) + blo(gb.z), 0.f); dot = fmaf(h, gp[4], dot);
      h = fmaxf(bhi(ga.z) + bhi(gb.z), 0.f); dot = fmaf(h, gp[5], dot);
      h = fmaxf(blo(ga.w) + blo(gb.w), 0.f); dot = fmaf(h, gp[6], dot);
      h = fmaxf(bhi(ga.w) + bhi(gb.w), 0.f); dot = fmaf(h, gp[7], dot);
    }
    dot += __shfl_xor(dot, 1, 64);
    dot += __shfl_xor(dot, 2, 64);
    float g = 1.f / (1.f + __expf(-(dot + gb2p[0])));
    float om = 1.f - g;
    #pragma unroll
    for (int cc = 0; cc < 4; ++cc) {
      int j = j0 + cc * 8;
      uint4 uu = *(const uint4*)(ps + 128 + j);
      uint4 vv = *(const uint4*)(pt + 128 + j);
      uint4 ee = *(const uint4*)&eatB[e][j];
      uint o0 = pk2(fmaxf(fmaf(g, blo(uu.x), om * blo(vv.x)) + blo(ee.x), 0.f),
                    fmaxf(fmaf(g, bhi(uu.x), om * bhi(vv.x)) + bhi(ee.x), 0.f));
      uint o1 = pk2(fmaxf(fmaf(g, blo(uu.y), om * blo(vv.y)) + blo(ee.y), 0.f),
                    fmaxf(fmaf(g, bhi(uu.y), om * bhi(vv.y)) + bhi(ee.y), 0.f));
      uint o2 = pk2(fmaxf(fmaf(g, blo(uu.z), om * blo(vv.z)) + blo(ee.z), 0.f),
                    fmaxf(fmaf(g, bhi(uu.z), om * bhi(vv.z)) + bhi(ee.z), 0.f));
      uint o3 = pk2(fmaxf(fmaf(g, blo(uu.w), om * blo(vv.w)) + blo(ee.w), 0.f),
                    fmaxf(fmaf(g, bhi(uu.w), om * bhi(vv.w)) + bhi(ee.w), 0.f));
      *(uint4*)&h1s[e][j] = make_uint4(o0, o1, o2, o3);
    }
  }
  __syncthreads();
  // Phase H: h2 = relu(h1 @ w2^T + b2)  (M=64, N=64, K=128) via MFMA
  {
    f32x4 zz = {0.f, 0.f, 0.f, 0.f};
    f32x4 acc[4] = {zz, zz, zz, zz};
    #pragma unroll
    for (int ks = 0; ks < 4; ++ks) {
      short8 a = *(const short8*)&h1s[w * 16 + (lane & 15)][ks * 32 + (lane >> 4) * 8];
      #pragma unroll
      for (int nf = 0; nf < 4; ++nf) {
        short8 b = *(const short8*)(w2B + (size_t)(nf * 16 + (lane & 15)) * 128 + ks * 32 + (lane >> 4) * 8);
        acc[nf] = MFMA16(a, b, acc[nf]);
      }
    }
    __syncthreads();   // eatB dead; h2F aliases it
    int ebase = w * 16 + (lane >> 4) * 4;
    #pragma unroll
    for (int nf = 0; nf < 4; ++nf) {
      int n = nf * 16 + (lane & 15);
      #pragma unroll
      for (int i = 0; i < 4; ++i)
        h2F[ebase + i][n] = fmaxf(acc[nf][i] + mb2s[n], 0.f);
    }
  }
  __syncthreads();
  // Phase O: out = h2 @ mw3^T + b3
  if (t < 128) {
    int e = t >> 1, o = t & 1;
    int eg = e0 + e;
    if (eg < E) {
      float s = mb3[o];
      #pragma unroll
      for (int kk = 0; kk < 64; kk += 4) {
        float4 hv = *(const float4*)&h2F[e][kk];
        float4 wv = *(const float4*)&mw3s[o * 64 + kk];
        s = fmaf(hv.x, wv.x, s); s = fmaf(hv.y, wv.y, s);
        s = fmaf(hv.z, wv.z, s); s = fmaf(hv.w, wv.w, s);
      }
      out[(size_t)eg * 2 + o] = s;
    }
  }
}

// ------------------------------------------------------------------- launch
extern "C" void kernel_launch(void* const* d_in, const int* in_sizes, int n_in,
                              void* d_out, int out_size, void* d_ws, size_t ws_size,
                              hipStream_t stream) {
  const float* x_source = (const float*)d_in[0];
  const float* x_target = (const float*)d_in[1];
  const float* edge_attr = (const float*)d_in[2];
  const float* enc_s_w1 = (const float*)d_in[3];
  const float* enc_s_b1 = (const float*)d_in[4];
  const float* enc_s_w2 = (const float*)d_in[5];
  const float* enc_s_b2 = (const float*)d_in[6];
  const float* enc_t_w1 = (const float*)d_in[7];
  const float* enc_t_b1 = (const float*)d_in[8];
  const float* enc_t_w2 = (const float*)d_in[9];
  const float* enc_t_b2 = (const float*)d_in[10];
  const float* conv_wl = (const float*)d_in[11];
  const float* conv_bl = (const float*)d_in[12];
  const float* conv_wr = (const float*)d_in[13];
  const float* gate_w1 = (const float*)d_in[14];
  const float* gate_b1 = (const float*)d_in[15];
  const float* gate_w2 = (const float*)d_in[16];
  const float* gate_b2 = (const float*)d_in[17];
  const float* mlp_w1 = (const float*)d_in[18];
  const float* mlp_b1 = (const float*)d_in[19];
  const float* mlp_w2 = (const float*)d_in[20];
  const float* mlp_b2 = (const float*)d_in[21];
  const float* mlp_w3 = (const float*)d_in[22];
  const float* mlp_b3 = (const float*)d_in[23];
  const int* ei[4] = {(const int*)d_in[24], (const int*)d_in[25],
                      (const int*)d_in[26], (const int*)d_in[27]};  // 0=ss,1=tt,2=st,3=ts
  float* out = (float*)d_out;

  char* wsp = (char*)d_ws;
  size_t off = 0;
  auto alloc = [&](size_t bytes) {
    char* p = wsp + off;
    off += (bytes + 255) & ~(size_t)255;
    return p;
  };
  const size_t NBE = (size_t)NSN * 128;          // elements per node buffer
  ushort* nbase = (ushort*)alloc(6 * NBE * 2);   // 6 rotating node buffers
  ushort* nb[6];
  for (int i = 0; i < 6; ++i) nb[i] = nbase + (size_t)i * NBE;
  int* adj4 = (int*)alloc((size_t)4 * EE * 4);
  int* off4 = (int*)alloc(4 * 50001 * 4);
  int* cur4 = (int*)alloc(4 * 50000 * 4);
  int* cnt4 = (int*)alloc(4 * 50000 * 4);
  ushort* xsB = (ushort*)alloc((size_t)NSN * 64 * 2);
  ushort* xtB = (ushort*)alloc((size_t)NTN * 64 * 2);
  ushort* esw1B = (ushort*)alloc(128 * 64 * 2);
  ushort* esw2B = (ushort*)alloc(128 * 128 * 2);
  ushort* etw1B = (ushort*)alloc(128 * 64 * 2);
  ushort* etw2B = (ushort*)alloc(128 * 128 * 2);
  ushort* wlB = (ushort*)alloc((size_t)12 * 16384 * 2);
  ushort* wrcB = (ushort*)alloc((size_t)6 * 16384 * 2);
  float* blc = (float*)alloc(6 * 128 * 4);
  ushort* PSg = (ushort*)alloc(16384 * 2);
  ushort* PTg = (ushort*)alloc(16384 * 2);
  ushort* WcB = (ushort*)alloc(16384 * 2);
  ushort* w1eB = (ushort*)alloc(128 * 32 * 2);
  ushort* w2B = (ushort*)alloc(64 * 128 * 2);

  // --- CSR build ---
  hipMemsetAsync(cnt4, 0, 4 * 50000 * sizeof(int), stream);
  int cb = (EE + 255) / 256;
  for (int r = 0; r < 4; ++r)
    count_k<<<cb, 256, 0, stream>>>(ei[r] + EE, cnt4 + (size_t)r * 50000, EE);
  scan_k<<<4, 256, 0, stream>>>(cnt4, off4, cur4);
  for (int r = 0; r < 4; ++r)
    fill_k<<<cb, 256, 0, stream>>>(ei[r], cur4 + (size_t)r * 50000, adj4 + (size_t)r * EE, EE);

  // --- weight + input conversion ---
  cvt_k<<<(8192 + 255) / 256, 256, 0, stream>>>(enc_s_w1, esw1B, 8192);
  cvt_k<<<(16384 + 255) / 256, 256, 0, stream>>>(enc_s_w2, esw2B, 16384);
  pad_cvt_k<<<(128 * 64 + 255) / 256, 256, 0, stream>>>(enc_t_w1, etw1B, 128, 48);
  cvt_k<<<(16384 + 255) / 256, 256, 0, stream>>>(enc_t_w2, etw2B, 16384);
  cvt_k<<<(196608 + 255) / 256, 256, 0, stream>>>(conv_wl, wlB, 196608);
  wrc_k<<<dim3(64, 6), 256, 0, stream>>>(conv_wr, conv_bl, wrcB, blc);
  headw_k<<<240, 256, 0, stream>>>(gate_w1, mlp_w1, mlp_w2, PSg, PTg, WcB, w1eB, w2B);
  cvt_k<<<(NSN * 64 + 255) / 256, 256, 0, stream>>>(x_source, xsB, NSN * 64);
  pad_cvt_k<<<(NTN * 64 + 255) / 256, 256, 0, stream>>>(x_target, xtB, NTN, 48);

  // --- encoders (nb2 as tmp) ---
  int gm = (NSN + 127) / 128;
  gemmN_k<1><<<gm, 256, 0, stream>>>(xsB, esw1B, enc_s_b1, nb[2], NSN, 64, 128);
  gemmN_k<0><<<gm, 256, 0, stream>>>(nb[2], esw2B, enc_s_b2, nb[0], NSN, 128, 128);
  gemmN_k<1><<<gm, 256, 0, stream>>>(xtB, etw1B, enc_t_b1, nb[2], NTN, 64, 128);
  gemmN_k<0><<<gm, 256, 0, stream>>>(nb[2], etw2B, enc_t_b2, nb[1], NTN, 128, 128);

  // --- 3 hetero layers; buffer schedule leaves (0,1) and (2,3) free at end ---
  int gb = (NSN + 7) / 8;
  int is = 0, it = 1;
  const int outS[3] = {4, 2, 4}, outT[3] = {5, 3, 5};
  const int mA[3] = {2, 0, 0}, mB[3] = {3, 1, 1};
  for (int l = 0; l < 3; ++l) {
    const ushort* wl0 = wlB + (size_t)(l * 4 + 0) * 16384;
    const ushort* wl1 = wlB + (size_t)(l * 4 + 1) * 16384;
    const ushort* wl2 = wlB + (size_t)(l * 4 + 2) * 16384;
    const ushort* wl3 = wlB + (size_t)(l * 4 + 3) * 16384;
    ushort* m0b = nb[mA[l]];
    ushort* m1b = nb[mB[l]];
    // dst = source: mean(hs via ss), mean(ht via ts)
    gather_k<<<gb, 256, 0, stream>>>(nb[is], off4 + 0 * 50001, adj4 + (size_t)0 * EE, m0b, NSN);
    gather_k<<<gb, 256, 0, stream>>>(nb[it], off4 + 3 * 50001, adj4 + (size_t)3 * EE, m1b, NSN);
    if (l == 0)
      gemm3_k<0><<<gm, 256, 0, stream>>>(m0b, m1b, nb[is], wl0, wl3,
          wrcB + (size_t)(l * 2 + 0) * 16384, blc + (l * 2 + 0) * 128, nullptr, nb[outS[l]], NSN);
    else
      gemm3_k<1><<<gm, 256, 0, stream>>>(m0b, m1b, nb[is], wl0, wl3,
          wrcB + (size_t)(l * 2 + 0) * 16384, blc + (l * 2 + 0) * 128, nb[is], nb[outS[l]], NSN);
    // dst = target: mean(ht via tt), mean(hs via st)
    gather_k<<<gb, 256, 0, stream>>>(nb[it], off4 + 1 * 50001, adj4 + (size_t)1 * EE, m0b, NTN);
    gather_k<<<gb, 256, 0, stream>>>(nb[is], off4 + 2 * 50001, adj4 + (size_t)2 * EE, m1b, NTN);
    if (l == 0)
      gemm3_k<0><<<gm, 256, 0, stream>>>(m0b, m1b, nb[it], wl1, wl2,
          wrcB + (size_t)(l * 2 + 1) * 16384, blc + (l * 2 + 1) * 128, nullptr, nb[outT[l]], NTN);
    else
      gemm3_k<1><<<gm, 256, 0, stream>>>(m0b, m1b, nb[it], wl1, wl2,
          wrcB + (size_t)(l * 2 + 1) * 16384, blc + (l * 2 + 1) * 128, nb[it], nb[outT[l]], NTN);
    is = outS[l]; it = outT[l];
  }
  // final: is=4 (h3s), it=5 (h3t); nb0..nb3 free

  // --- nodewise head precomputes: pS/pT [N][256] = [gate_part | u'(+mb1)] ---
  ushort* pS = nbase;                 // overlays nb0,nb1 (free)
  ushort* pT = nbase + 2 * NBE;       // overlays nb2,nb3 (free)
  gemmN_k<0><<<gm, 256, 0, stream>>>(nb[4], PSg, gate_b1, pS, NSN, 128, 256);
  gemmN_k<0><<<gm, 256, 0, stream>>>(nb[4], WcB, mlp_b1, pS + 128, NSN, 128, 256);
  gemmN_k<0><<<gm, 256, 0, stream>>>(nb[5], PTg, nullptr, pT, NTN, 128, 256);
  gemmN_k<0><<<gm, 256, 0, stream>>>(nb[5], WcB, mlp_b1, pT + 128, NTN, 128, 256);

  // --- fused edge head ---
  head_k<<<(EE + 63) / 64, 256, 0, stream>>>(pS, pT, ei[2], edge_attr, w1eB, w2B,
      gate_w2, gate_b2, mlp_b2, mlp_w3, mlp_b3, out, EE);
}